// Round 10
// baseline (190.292 us; speedup 1.0000x reference)
//
#include <hip/hip_runtime.h>
#include <math.h>

#define B_      64
#define S_      128
#define KN      16
#define EE      128
#define HH      100
#define NTREE   8192            // B_*S_

typedef __attribute__((ext_vector_type(8))) short   bf8;    // 8 bf16 (4 VGPRs)
typedef __attribute__((ext_vector_type(4))) float   f32x4;
typedef __attribute__((ext_vector_type(8))) float   f32x8;
typedef __attribute__((ext_vector_type(4))) unsigned int u32x4;

// workspace byte offsets (256-aligned)
#define EMB_BF_OFF   0u           // 50000*128*2 = 12,800,000
#define WC_BF_OFF    12800000u    // 128*128*2   = 32,768
#define WIH_BF_OFF   12832768u    // 768*128*2   = 196,608 (padded [dir][g][128j][128k])
#define WHH_BF_OFF   13029376u    // 768*128*2   = 196,608 (padded, zero pads)
#define ENC_BF_OFF   13225984u    // 16384*128*2 = 4,194,304   rows = e*8192 + t*64 + b
#define HMAX_OFF     17420288u    // 25600*4     = 102,400

__constant__ float c_cnt[16] = {16.f,8.f,7.f,4.f,3.f,3.f,3.f,2.f,
                                1.f,1.f,1.f,1.f,1.f,1.f,1.f,1.f};

__device__ __forceinline__ float bf2f(unsigned short u) {
    unsigned int x = ((unsigned int)u) << 16;
    return __builtin_bit_cast(float, x);
}
__device__ __forceinline__ unsigned short f2bf(float f) {
    unsigned int x = __builtin_bit_cast(unsigned int, f);
    x = x + 0x7fffu + ((x >> 16) & 1u);          // RNE
    return (unsigned short)(x >> 16);
}
__device__ __forceinline__ f32x8 cvt8(const bf8& v) {
    f32x8 f;
    #pragma unroll
    for (int q = 0; q < 8; ++q) f[q] = bf2f((unsigned short)v[q]);
    return f;
}
__device__ __forceinline__ f32x8 shx(const f32x8& v, int m) {
    f32x8 o;
    #pragma unroll
    for (int q = 0; q < 8; ++q) o[q] = __shfl_xor(v[q], m);
    return o;
}
__device__ __forceinline__ bf8 pack8(const f32x8& v) {
    bf8 o;
    #pragma unroll
    for (int q = 0; q < 8; ++q) o[q] = (short)f2bf(v[q]);
    return o;
}
// swizzle a 16B-aligned column-byte offset within a 256B row
#define SWZ(row, cb) ((cb) ^ (((row) & 7) << 4))

// ---------------------------------------------------------------------------
// K0: fp32 -> bf16 prep: emb, Wc, wih padded [2][3][128][128], whh padded same
// ---------------------------------------------------------------------------
#define NA 1600000   // emb float4s
#define NB 4096      // Wc float4s
#define NC 24576     // wih_pad ushort4s (768*128/4)
#define ND 24576     // whh_pad ushort4s
__global__ __launch_bounds__(256) void k_prep(
    const float* __restrict__ emb, const float* __restrict__ Wc,
    const float* __restrict__ wih_f, const float* __restrict__ wih_b,
    const float* __restrict__ whh_f, const float* __restrict__ whh_b,
    unsigned short* __restrict__ emb_bf, unsigned short* __restrict__ wc_bf,
    unsigned short* __restrict__ wih_pad, unsigned short* __restrict__ whh_pad)
{
    const int i = blockIdx.x * 256 + threadIdx.x;
    if (i < NA + NB) {
        const float* src = (i < NA) ? emb : Wc;
        unsigned short* dst = (i < NA) ? emb_bf : wc_bf;
        const int j = (i < NA) ? i : i - NA;
        float4 v = ((const float4*)src)[j];
        ushort4 o;
        o.x = f2bf(v.x); o.y = f2bf(v.y); o.z = f2bf(v.z); o.w = f2bf(v.w);
        ((ushort4*)dst)[j] = o;
    } else if (i < NA + NB + NC) {
        const int u = i - NA - NB;                  // 0..24575
        const int row = u >> 5, k4 = u & 31;        // row 0..767
        const int dir = row / 384, rem = row % 384, g = rem >> 7, j = rem & 127;
        ushort4 o = {0, 0, 0, 0};
        if (j < 100) {
            const float* w = dir ? wih_b : wih_f;   // [300][128]
            float4 v = ((const float4*)w)[(g * 100 + j) * 32 + k4];
            o.x = f2bf(v.x); o.y = f2bf(v.y); o.z = f2bf(v.z); o.w = f2bf(v.w);
        }
        ((ushort4*)wih_pad)[u] = o;
    } else if (i < NA + NB + NC + ND) {
        const int u = i - NA - NB - NC;
        const int row = u >> 5, k0 = (u & 31) * 4;
        const int dir = row / 384, rem = row % 384, g = rem >> 7, j = rem & 127;
        ushort4 o = {0, 0, 0, 0};
        if (j < 100) {
            const float* w = dir ? whh_b : whh_f;   // [300][100]
            const float* wr = w + (g * 100 + j) * 100;
            unsigned short t[4];
            #pragma unroll
            for (int q = 0; q < 4; ++q)
                t[q] = (k0 + q < 100) ? f2bf(wr[k0 + q]) : (unsigned short)0;
            o.x = t[0]; o.y = t[1]; o.z = t[2]; o.w = t[3];
        }
        ((ushort4*)whh_pad)[u] = o;
    }
}

// ---------------------------------------------------------------------------
// K1: gather bf16 emb (all 512 threads) -> shfl-based tree aggregation ->
// bf16 A tile; B = Wc bf16. MFMA 16x16x32; epilogue: +cnt*bc, per-tree max,
// relu. (unchanged)
// ---------------------------------------------------------------------------
__global__ __launch_bounds__(512) void k_encode(
    const int* __restrict__ tok1, const int* __restrict__ tok2,
    const unsigned short* __restrict__ emb_bf,
    const unsigned short* __restrict__ wc_bf,
    const float* __restrict__ bc,
    unsigned short* __restrict__ enc_bf)
{
    __shared__ unsigned short A_lds[128 * 128];   // [row][k] swizzled (32KB)
    __shared__ unsigned short B_lds[128 * 128];   // [col][k] swizzled (32KB)
    const int tid = threadIdx.x;
    const int blk = blockIdx.x;
    const int e = blk >> 10;
    const int tree0 = (blk & 1023) * 8;
    const int* __restrict__ tok = e ? tok2 : tok1;

    const int lane = tid & 63;
    const int tr  = tid >> 6;        // tree 0..7 (== wave)
    const int ng  = lane >> 4;       // node group: nodes ng*4..ng*4+3
    const int seg = lane & 15;       // 8-dim segment

    u32x4 wcv[4];
    #pragma unroll
    for (int it = 0; it < 4; ++it) {
        const int idx = tid + 512 * it;          // 0..2047
        wcv[it] = *(const u32x4*)(wc_bf + (idx >> 4) * EE + (idx & 15) * 8);
    }

    const int tb = (tree0 + tr) * KN + ng * 4;
    const int tk0 = tok[tb + 0], tk1 = tok[tb + 1], tk2 = tok[tb + 2], tk3 = tok[tb + 3];
    f32x8 a0 = cvt8(*(const bf8*)(emb_bf + (size_t)tk0 * EE + seg * 8));
    f32x8 a1 = cvt8(*(const bf8*)(emb_bf + (size_t)tk1 * EE + seg * 8));
    f32x8 a2 = cvt8(*(const bf8*)(emb_bf + (size_t)tk2 * EE + seg * 8));
    f32x8 a3 = cvt8(*(const bf8*)(emb_bf + (size_t)tk3 * EE + seg * 8));

    {
        f32x8 t0 = shx(a3, 32);
        if (ng == 1) a3 += t0;
        f32x8 u1 = shx(a3, 16), u2 = shx(a0, 32);
        if (ng == 0) a3 += u1 + u2;
        f32x8 v1 = shx(a1, 48), v2 = shx(a2, 48);
        if (ng == 1) a0 += v1 + v2;
        f32x8 w1 = shx(a3, 48), w2 = shx(a0, 32);
        if (ng == 1) a1 += w1 + w2;
        f32x8 x1 = shx(a1, 32), x2 = shx(a2, 32);
        if (ng == 1) a2 += x1 + x2;
        f32x8 z1 = shx(a0, 16);
        if (ng == 0) a1 += a3 + z1;
        f32x8 z2 = shx(a1, 16), z3 = shx(a2, 16);
        if (ng == 0) a2 += z2 + z3;
        if (ng == 0) a0 += a1 + a2;
    }

    {
        const int r0 = tr * 16 + ng * 4;
        *(bf8*)((char*)A_lds + (r0+0) * 256 + SWZ(r0+0, seg * 16)) = pack8(a0);
        *(bf8*)((char*)A_lds + (r0+1) * 256 + SWZ(r0+1, seg * 16)) = pack8(a1);
        *(bf8*)((char*)A_lds + (r0+2) * 256 + SWZ(r0+2, seg * 16)) = pack8(a2);
        *(bf8*)((char*)A_lds + (r0+3) * 256 + SWZ(r0+3, seg * 16)) = pack8(a3);
    }
    #pragma unroll
    for (int it = 0; it < 4; ++it) {
        const int idx = tid + 512 * it;
        const int row = idx >> 4, sg = idx & 15;
        *(u32x4*)((char*)B_lds + row * 256 + SWZ(row, sg * 16)) = wcv[it];
    }
    __syncthreads();

    const int wid = tid >> 6;
    const int wr = wid >> 1, wc = wid & 1;
    const int l15 = lane & 15, lg = lane >> 4;

    f32x4 acc[2][4];
    #pragma unroll
    for (int rt = 0; rt < 2; ++rt)
        #pragma unroll
        for (int ct = 0; ct < 4; ++ct) acc[rt][ct] = (f32x4){0.f, 0.f, 0.f, 0.f};

    #pragma unroll
    for (int ks = 0; ks < 4; ++ks) {
        bf8 aF[2], bF[4];
        #pragma unroll
        for (int rt = 0; rt < 2; ++rt) {
            const int row = wr * 32 + rt * 16 + l15;
            aF[rt] = *(const bf8*)((const char*)A_lds + row * 256 + SWZ(row, ks * 64 + lg * 16));
        }
        #pragma unroll
        for (int ct = 0; ct < 4; ++ct) {
            const int col = wc * 64 + ct * 16 + l15;
            bF[ct] = *(const bf8*)((const char*)B_lds + col * 256 + SWZ(col, ks * 64 + lg * 16));
        }
        #pragma unroll
        for (int rt = 0; rt < 2; ++rt)
            #pragma unroll
            for (int ct = 0; ct < 4; ++ct)
                acc[rt][ct] = __builtin_amdgcn_mfma_f32_16x16x32_bf16(aF[rt], bF[ct], acc[rt][ct], 0, 0, 0);
    }

    #pragma unroll
    for (int rt = 0; rt < 2; ++rt) {
        const int ltree = wr * 2 + rt;
        #pragma unroll
        for (int ct = 0; ct < 4; ++ct) {
            const int col = wc * 64 + ct * 16 + l15;
            const float bcv = bc[col];
            f32x4 v = acc[rt][ct];
            float m = -1e30f;
            #pragma unroll
            for (int r = 0; r < 4; ++r)
                m = fmaxf(m, v[r] + c_cnt[lg * 4 + r] * bcv);
            m = fmaxf(m, __shfl_xor(m, 16));
            m = fmaxf(m, __shfl_xor(m, 32));
            m = fmaxf(m, 0.f);
            if (lg == 0) {
                const int gtree = tree0 + ltree;
                const int row = (gtree & 127) * 64 + (gtree >> 7);   // t*64 + b
                enc_bf[((size_t)e * NTREE + row) * EE + col] = f2bf(m);
            }
        }
    }
}

// ---------------------------------------------------------------------------
// K3: fused GRU scan. 64 blocks (e, dir, bgroup-of-4) x 448 thr (7 waves).
// R10: phase-overlap pipeline — ih-GEMM for step t+1 (enc-only, independent
// of h) is issued between step t's hh-MFMAs and gates, so gate VALU overlaps
// ih MFMA instead of serializing (R9 counters showed VALU+MFMA+LDS summing).
// r,z hh-MFMAs continue into the saved ih accumulators (no adds); n kept
// split per GRU semantics. setprio(1) around the hh cluster.
// ---------------------------------------------------------------------------
__global__ __launch_bounds__(448, 2) void k_gru(
    const unsigned short* __restrict__ enc_bf,
    const unsigned short* __restrict__ wih_pad,
    const unsigned short* __restrict__ whh_pad,
    const float* __restrict__ bih_f, const float* __restrict__ bih_b,
    const float* __restrict__ bhh_f, const float* __restrict__ bhh_b,
    float* __restrict__ hmax_out)
{
    __shared__ unsigned char h_lds[2][4 * 256];   // [buf][seq][rotated chunks] 2KB
    const int tid  = threadIdx.x;
    const int blk  = blockIdx.x;        // 64
    const int e    = blk >> 5;
    const int dir  = (blk >> 4) & 1;
    const int b0   = (blk & 15) * 4;
    const int lane = tid & 63;
    const int l15  = lane & 15;
    const int lg   = lane >> 4;
    const int c    = l15 & 3;           // seq column (x4 duplicated)
    const int jbase = (tid >> 6) * 16;

    for (int u = tid; u < 512; u += 448)
        ((unsigned int*)h_lds)[u] = 0u;

    // weight A-frags: row j = jbase + l15, k = ks*32 + lg*8
    bf8 aI[3][4], aH[3][4];
    {
        const unsigned short* wiP = wih_pad + (size_t)dir * 3 * 128 * 128;
        const unsigned short* whP = whh_pad + (size_t)dir * 3 * 128 * 128;
        #pragma unroll
        for (int g = 0; g < 3; ++g)
            #pragma unroll
            for (int ks = 0; ks < 4; ++ks) {
                const size_t ro = (size_t)(g * 128 + jbase + l15) * 128 + ks * 32 + lg * 8;
                aI[g][ks] = *(const bf8*)(wiP + ro);
                aH[g][ks] = *(const bf8*)(whP + ro);
                asm volatile("" : "+v"(aI[g][ks]));
                asm volatile("" : "+v"(aH[g][ks]));
            }
    }
    // biases folded into acc init: reg r <-> row j = jbase + lg*4 + r
    const float* __restrict__ bih = dir ? bih_b : bih_f;
    const float* __restrict__ bhh = dir ? bhh_b : bhh_f;
    f32x4 bR, bZ, bI_, bH_;
    #pragma unroll
    for (int r = 0; r < 4; ++r) {
        const int j = jbase + lg * 4 + r;
        bR[r]  = (j < 100) ? bih[j]       + bhh[j]       : 0.f;
        bZ[r]  = (j < 100) ? bih[100 + j] + bhh[100 + j] : 0.f;
        bI_[r] = (j < 100) ? bih[200 + j] : 0.f;
        bH_[r] = (j < 100) ? bhh[200 + j] : 0.f;
    }

    const unsigned short* encp =
        enc_bf + ((size_t)e * NTREE + b0 + c) * EE + lg * 8;

    // depth-4 enc prefetch: named sets (static indexing)
    bf8 e0[4], e1[4], e2[4], e3[4];
    {
        const int t0 = dir ? 127 : 0, t1 = dir ? 126 : 1;
        const int t2 = dir ? 125 : 2, t3 = dir ? 124 : 3;
        #pragma unroll
        for (int ks = 0; ks < 4; ++ks) {
            e0[ks] = *(const bf8*)(encp + (size_t)t0 * 8192 + ks * 32);
            e1[ks] = *(const bf8*)(encp + (size_t)t1 * 8192 + ks * 32);
            e2[ks] = *(const bf8*)(encp + (size_t)t2 * 8192 + ks * 32);
            e3[ks] = *(const bf8*)(encp + (size_t)t3 * 8192 + ks * 32);
        }
    }

    // pipelined ih accumulators for the CURRENT step (biases included)
    f32x4 pR = bR, pZ = bZ, pN = bI_;
    #pragma unroll
    for (int ks = 0; ks < 4; ++ks) {
        pR = __builtin_amdgcn_mfma_f32_16x16x32_bf16(aI[0][ks], e0[ks], pR, 0, 0, 0);
        pZ = __builtin_amdgcn_mfma_f32_16x16x32_bf16(aI[1][ks], e0[ks], pZ, 0, 0, 0);
        pN = __builtin_amdgcn_mfma_f32_16x16x32_bf16(aI[2][ks], e0[ks], pN, 0, 0, 0);
    }

    f32x4 h_cur = (f32x4){0.f, 0.f, 0.f, 0.f};
    f32x4 hmx   = (f32x4){-1e30f, -1e30f, -1e30f, -1e30f};
    // h write address (only lanes l15<4 write): 8B at rotated chunk
    const unsigned int hw_off = c * 256
        + ((((jbase >> 3) + (lg >> 1) + 4 * c) & 15) << 4) + (lg & 1) * 8;
    __syncthreads();

#define L2E  1.4426950408889634f
// EFN: frag set holding enc(S+1) (consumed for next-step ih)
// EFR: frag set to refill with enc(S+4)
#define GRU_STEP(EFN, EFR, P, S)                                               \
    {                                                                          \
        bf8 hF[4];                                                             \
        const unsigned char* hb = h_lds[P] + c * 256;                          \
        _Pragma("unroll")                                                      \
        for (int ks = 0; ks < 4; ++ks)                                         \
            hF[ks] = *(const bf8*)(hb + (((ks * 4 + lg + 4 * c) & 15) << 4));  \
        /* hh MFMAs: r,z continue into saved ih accs; n fresh */               \
        f32x4 aHn = bH_;                                                       \
        __builtin_amdgcn_s_setprio(1);                                         \
        _Pragma("unroll")                                                      \
        for (int ks = 0; ks < 4; ++ks) {                                       \
            pR  = __builtin_amdgcn_mfma_f32_16x16x32_bf16(aH[0][ks], hF[ks], pR, 0, 0, 0); \
            pZ  = __builtin_amdgcn_mfma_f32_16x16x32_bf16(aH[1][ks], hF[ks], pZ, 0, 0, 0); \
            aHn = __builtin_amdgcn_mfma_f32_16x16x32_bf16(aH[2][ks], hF[ks], aHn, 0, 0, 0); \
        }                                                                      \
        __builtin_amdgcn_s_setprio(0);                                         \
        const f32x4 gR = pR, gZ = pZ, gN = pN;                                 \
        /* next step's ih (independent of h) overlaps the gates below */       \
        pR = bR; pZ = bZ; pN = bI_;                                            \
        if ((S) + 1 < S_) {                                                    \
            _Pragma("unroll")                                                  \
            for (int ks = 0; ks < 4; ++ks) {                                   \
                pR = __builtin_amdgcn_mfma_f32_16x16x32_bf16(aI[0][ks], EFN[ks], pR, 0, 0, 0); \
                pZ = __builtin_amdgcn_mfma_f32_16x16x32_bf16(aI[1][ks], EFN[ks], pZ, 0, 0, 0); \
                pN = __builtin_amdgcn_mfma_f32_16x16x32_bf16(aI[2][ks], EFN[ks], pN, 0, 0, 0); \
            }                                                                  \
        }                                                                      \
        if ((S) + 4 < S_) {                                                    \
            const int tmn = dir ? (127 - ((S) + 4)) : ((S) + 4);               \
            _Pragma("unroll")                                                  \
            for (int ks = 0; ks < 4; ++ks)                                     \
                EFR[ks] = *(const bf8*)(encp + (size_t)tmn * 8192 + ks * 32);  \
        }                                                                      \
        unsigned short hq[4];                                                  \
        _Pragma("unroll")                                                      \
        for (int r = 0; r < 4; ++r) {                                          \
            const float rg  = __builtin_amdgcn_rcpf(1.f + __builtin_amdgcn_exp2f(-L2E * gR[r])); \
            const float zg  = __builtin_amdgcn_rcpf(1.f + __builtin_amdgcn_exp2f(-L2E * gZ[r])); \
            const float nx  = gN[r] + rg * aHn[r];                             \
            const float ng  = 1.f - 2.f * __builtin_amdgcn_rcpf(1.f + __builtin_amdgcn_exp2f((2.f * L2E) * nx)); \
            const float hnew = ng + zg * (h_cur[r] - ng);                      \
            h_cur[r] = hnew;                                                   \
            hmx[r] = fmaxf(hmx[r], hnew);                                      \
            hq[r] = f2bf(hnew);                                                \
        }                                                                      \
        if (l15 < 4) {                                                         \
            ushort4 hv; hv.x = hq[0]; hv.y = hq[1]; hv.z = hq[2]; hv.w = hq[3];\
            *(ushort4*)(h_lds[(P) ^ 1] + hw_off) = hv;                         \
        }                                                                      \
        __builtin_amdgcn_sched_barrier(0);                                     \
        asm volatile("s_waitcnt lgkmcnt(0)");                                  \
        __builtin_amdgcn_s_barrier();                                          \
        __builtin_amdgcn_sched_barrier(0);                                     \
    }

    for (int t = 0; t < S_; t += 4) {
        GRU_STEP(e1, e0, 0, t)
        GRU_STEP(e2, e1, 1, t + 1)
        GRU_STEP(e3, e2, 0, t + 2)
        GRU_STEP(e0, e3, 1, t + 3)
    }
#undef GRU_STEP

    if (l15 < 4) {
        #pragma unroll
        for (int r = 0; r < 4; ++r) {
            const int j = jbase + lg * 4 + r;
            if (j < 100)
                hmax_out[((size_t)((e * 2 + dir) * 64 + b0 + c)) * HH + j] = hmx[r];
        }
    }
}

// ---------------------------------------------------------------------------
// K4: fc + softmax
// ---------------------------------------------------------------------------
__global__ void k_final(const float* __restrict__ hmax,
                        const float* __restrict__ fcw,
                        const float* __restrict__ fcb,
                        float* __restrict__ out)
{
    const int b = threadIdx.x;
    if (b >= B_) return;
    float y0 = fcb[0], y1 = fcb[1];
    for (int m = 0; m < 400; ++m) {
        const int e   = m / 200;
        const int dm  = m % 200;
        const int dir = dm / 100;
        const int j   = dm % 100;
        const float x = hmax[((size_t)((e * 2 + dir) * 64 + b)) * HH + j];
        y0 += fcw[m]       * x;
        y1 += fcw[400 + m] * x;
    }
    const float mx = fmaxf(y0, y1);
    const float e0 = __expf(y0 - mx), e1 = __expf(y1 - mx);
    const float s = e0 + e1;
    out[b * 2]     = e0 / s;
    out[b * 2 + 1] = e1 / s;
}

extern "C" void kernel_launch(void* const* d_in, const int* in_sizes, int n_in,
                              void* d_out, int out_size, void* d_ws, size_t ws_size,
                              hipStream_t stream)
{
    const int*   tok1  = (const int*)d_in[0];
    const int*   tok2  = (const int*)d_in[1];
    const float* emb   = (const float*)d_in[4];
    const float* Wc    = (const float*)d_in[5];
    const float* bc    = (const float*)d_in[6];
    const float* wih_f = (const float*)d_in[7];
    const float* whh_f = (const float*)d_in[8];
    const float* bih_f = (const float*)d_in[9];
    const float* bhh_f = (const float*)d_in[10];
    const float* wih_b = (const float*)d_in[11];
    const float* whh_b = (const float*)d_in[12];
    const float* bih_b = (const float*)d_in[13];
    const float* bhh_b = (const float*)d_in[14];
    const float* fcw   = (const float*)d_in[15];
    const float* fcb   = (const float*)d_in[16];

    char* ws = (char*)d_ws;
    unsigned short* emb_bf  = (unsigned short*)(ws + EMB_BF_OFF);
    unsigned short* wc_bf   = (unsigned short*)(ws + WC_BF_OFF);
    unsigned short* wih_pad = (unsigned short*)(ws + WIH_BF_OFF);
    unsigned short* whh_pad = (unsigned short*)(ws + WHH_BF_OFF);
    unsigned short* enc_bf  = (unsigned short*)(ws + ENC_BF_OFF);
    float*          hmax    = (float*)(ws + HMAX_OFF);

    k_prep<<<6458, 256, 0, stream>>>(emb, Wc, wih_f, wih_b, whh_f, whh_b,
                                     emb_bf, wc_bf, wih_pad, whh_pad);
    k_encode<<<2048, 512, 0, stream>>>(tok1, tok2, emb_bf, wc_bf, bc, enc_bf);
    k_gru<<<64, 448, 0, stream>>>(enc_bf, wih_pad, whh_pad,
                                  bih_f, bih_b, bhh_f, bhh_b, hmax);
    k_final<<<1, 64, 0, stream>>>(hmax, fcw, fcb, (float*)d_out);
}

// Round 11
// 157.715 us; speedup vs baseline: 1.2066x; 1.2066x over previous
//
#include <hip/hip_runtime.h>
#include <math.h>

#define B_      64
#define S_      128
#define KN      16
#define EE      128
#define HH      100
#define NTREE   8192            // B_*S_

typedef __attribute__((ext_vector_type(8))) short   bf8;    // 8 bf16 (4 VGPRs)
typedef __attribute__((ext_vector_type(4))) float   f32x4;
typedef __attribute__((ext_vector_type(8))) float   f32x8;
typedef __attribute__((ext_vector_type(4))) unsigned int u32x4;

// workspace byte offsets (256-aligned)
#define EMB_BF_OFF   0u           // 50000*128*2 = 12,800,000
#define WC_BF_OFF    12800000u    // 128*128*2   = 32,768
#define WIH_BF_OFF   12832768u    // 768*128*2   = 196,608 (padded [dir][g][128j][128k])
#define WHH_BF_OFF   13029376u    // 768*128*2   = 196,608 (padded, zero pads)
#define ENC_BF_OFF   13225984u    // 16384*128*2 = 4,194,304   rows = e*8192 + t*64 + b
#define HMAX_OFF     17420288u    // 25600*4     = 102,400

__constant__ float c_cnt[16] = {16.f,8.f,7.f,4.f,3.f,3.f,3.f,2.f,
                                1.f,1.f,1.f,1.f,1.f,1.f,1.f,1.f};

__device__ __forceinline__ float bf2f(unsigned short u) {
    unsigned int x = ((unsigned int)u) << 16;
    return __builtin_bit_cast(float, x);
}
__device__ __forceinline__ unsigned short f2bf(float f) {
    unsigned int x = __builtin_bit_cast(unsigned int, f);
    x = x + 0x7fffu + ((x >> 16) & 1u);          // RNE
    return (unsigned short)(x >> 16);
}
__device__ __forceinline__ f32x8 cvt8(const bf8& v) {
    f32x8 f;
    #pragma unroll
    for (int q = 0; q < 8; ++q) f[q] = bf2f((unsigned short)v[q]);
    return f;
}
__device__ __forceinline__ f32x8 shx(const f32x8& v, int m) {
    f32x8 o;
    #pragma unroll
    for (int q = 0; q < 8; ++q) o[q] = __shfl_xor(v[q], m);
    return o;
}
__device__ __forceinline__ bf8 pack8(const f32x8& v) {
    bf8 o;
    #pragma unroll
    for (int q = 0; q < 8; ++q) o[q] = (short)f2bf(v[q]);
    return o;
}
__device__ __forceinline__ float selq(const f32x4& v, int q) {
    const float a = (q & 1) ? v[1] : v[0];
    const float b = (q & 1) ? v[3] : v[2];
    return (q & 2) ? b : a;
}
// swizzle a 16B-aligned column-byte offset within a 256B row
#define SWZ(row, cb) ((cb) ^ (((row) & 7) << 4))

// ---------------------------------------------------------------------------
// K0: fp32 -> bf16 prep: emb, Wc, wih padded [2][3][128][128], whh padded same
// ---------------------------------------------------------------------------
#define NA 1600000   // emb float4s
#define NB 4096      // Wc float4s
#define NC 24576     // wih_pad ushort4s (768*128/4)
#define ND 24576     // whh_pad ushort4s
__global__ __launch_bounds__(256) void k_prep(
    const float* __restrict__ emb, const float* __restrict__ Wc,
    const float* __restrict__ wih_f, const float* __restrict__ wih_b,
    const float* __restrict__ whh_f, const float* __restrict__ whh_b,
    unsigned short* __restrict__ emb_bf, unsigned short* __restrict__ wc_bf,
    unsigned short* __restrict__ wih_pad, unsigned short* __restrict__ whh_pad)
{
    const int i = blockIdx.x * 256 + threadIdx.x;
    if (i < NA + NB) {
        const float* src = (i < NA) ? emb : Wc;
        unsigned short* dst = (i < NA) ? emb_bf : wc_bf;
        const int j = (i < NA) ? i : i - NA;
        float4 v = ((const float4*)src)[j];
        ushort4 o;
        o.x = f2bf(v.x); o.y = f2bf(v.y); o.z = f2bf(v.z); o.w = f2bf(v.w);
        ((ushort4*)dst)[j] = o;
    } else if (i < NA + NB + NC) {
        const int u = i - NA - NB;                  // 0..24575
        const int row = u >> 5, k4 = u & 31;        // row 0..767
        const int dir = row / 384, rem = row % 384, g = rem >> 7, j = rem & 127;
        ushort4 o = {0, 0, 0, 0};
        if (j < 100) {
            const float* w = dir ? wih_b : wih_f;   // [300][128]
            float4 v = ((const float4*)w)[(g * 100 + j) * 32 + k4];
            o.x = f2bf(v.x); o.y = f2bf(v.y); o.z = f2bf(v.z); o.w = f2bf(v.w);
        }
        ((ushort4*)wih_pad)[u] = o;
    } else if (i < NA + NB + NC + ND) {
        const int u = i - NA - NB - NC;
        const int row = u >> 5, k0 = (u & 31) * 4;
        const int dir = row / 384, rem = row % 384, g = rem >> 7, j = rem & 127;
        ushort4 o = {0, 0, 0, 0};
        if (j < 100) {
            const float* w = dir ? whh_b : whh_f;   // [300][100]
            const float* wr = w + (g * 100 + j) * 100;
            unsigned short t[4];
            #pragma unroll
            for (int q = 0; q < 4; ++q)
                t[q] = (k0 + q < 100) ? f2bf(wr[k0 + q]) : (unsigned short)0;
            o.x = t[0]; o.y = t[1]; o.z = t[2]; o.w = t[3];
        }
        ((ushort4*)whh_pad)[u] = o;
    }
}

// ---------------------------------------------------------------------------
// K1: gather bf16 emb (all 512 threads) -> shfl-based tree aggregation ->
// bf16 A tile; B = Wc bf16. MFMA 16x16x32; epilogue: +cnt*bc, per-tree max,
// relu. (unchanged)
// ---------------------------------------------------------------------------
__global__ __launch_bounds__(512) void k_encode(
    const int* __restrict__ tok1, const int* __restrict__ tok2,
    const unsigned short* __restrict__ emb_bf,
    const unsigned short* __restrict__ wc_bf,
    const float* __restrict__ bc,
    unsigned short* __restrict__ enc_bf)
{
    __shared__ unsigned short A_lds[128 * 128];   // [row][k] swizzled (32KB)
    __shared__ unsigned short B_lds[128 * 128];   // [col][k] swizzled (32KB)
    const int tid = threadIdx.x;
    const int blk = blockIdx.x;
    const int e = blk >> 10;
    const int tree0 = (blk & 1023) * 8;
    const int* __restrict__ tok = e ? tok2 : tok1;

    const int lane = tid & 63;
    const int tr  = tid >> 6;        // tree 0..7 (== wave)
    const int ng  = lane >> 4;       // node group: nodes ng*4..ng*4+3
    const int seg = lane & 15;       // 8-dim segment

    u32x4 wcv[4];
    #pragma unroll
    for (int it = 0; it < 4; ++it) {
        const int idx = tid + 512 * it;          // 0..2047
        wcv[it] = *(const u32x4*)(wc_bf + (idx >> 4) * EE + (idx & 15) * 8);
    }

    const int tb = (tree0 + tr) * KN + ng * 4;
    const int tk0 = tok[tb + 0], tk1 = tok[tb + 1], tk2 = tok[tb + 2], tk3 = tok[tb + 3];
    f32x8 a0 = cvt8(*(const bf8*)(emb_bf + (size_t)tk0 * EE + seg * 8));
    f32x8 a1 = cvt8(*(const bf8*)(emb_bf + (size_t)tk1 * EE + seg * 8));
    f32x8 a2 = cvt8(*(const bf8*)(emb_bf + (size_t)tk2 * EE + seg * 8));
    f32x8 a3 = cvt8(*(const bf8*)(emb_bf + (size_t)tk3 * EE + seg * 8));

    {
        f32x8 t0 = shx(a3, 32);
        if (ng == 1) a3 += t0;
        f32x8 u1 = shx(a3, 16), u2 = shx(a0, 32);
        if (ng == 0) a3 += u1 + u2;
        f32x8 v1 = shx(a1, 48), v2 = shx(a2, 48);
        if (ng == 1) a0 += v1 + v2;
        f32x8 w1 = shx(a3, 48), w2 = shx(a0, 32);
        if (ng == 1) a1 += w1 + w2;
        f32x8 x1 = shx(a1, 32), x2 = shx(a2, 32);
        if (ng == 1) a2 += x1 + x2;
        f32x8 z1 = shx(a0, 16);
        if (ng == 0) a1 += a3 + z1;
        f32x8 z2 = shx(a1, 16), z3 = shx(a2, 16);
        if (ng == 0) a2 += z2 + z3;
        if (ng == 0) a0 += a1 + a2;
    }

    {
        const int r0 = tr * 16 + ng * 4;
        *(bf8*)((char*)A_lds + (r0+0) * 256 + SWZ(r0+0, seg * 16)) = pack8(a0);
        *(bf8*)((char*)A_lds + (r0+1) * 256 + SWZ(r0+1, seg * 16)) = pack8(a1);
        *(bf8*)((char*)A_lds + (r0+2) * 256 + SWZ(r0+2, seg * 16)) = pack8(a2);
        *(bf8*)((char*)A_lds + (r0+3) * 256 + SWZ(r0+3, seg * 16)) = pack8(a3);
    }
    #pragma unroll
    for (int it = 0; it < 4; ++it) {
        const int idx = tid + 512 * it;
        const int row = idx >> 4, sg = idx & 15;
        *(u32x4*)((char*)B_lds + row * 256 + SWZ(row, sg * 16)) = wcv[it];
    }
    __syncthreads();

    const int wid = tid >> 6;
    const int wr = wid >> 1, wc = wid & 1;
    const int l15 = lane & 15, lg = lane >> 4;

    f32x4 acc[2][4];
    #pragma unroll
    for (int rt = 0; rt < 2; ++rt)
        #pragma unroll
        for (int ct = 0; ct < 4; ++ct) acc[rt][ct] = (f32x4){0.f, 0.f, 0.f, 0.f};

    #pragma unroll
    for (int ks = 0; ks < 4; ++ks) {
        bf8 aF[2], bF[4];
        #pragma unroll
        for (int rt = 0; rt < 2; ++rt) {
            const int row = wr * 32 + rt * 16 + l15;
            aF[rt] = *(const bf8*)((const char*)A_lds + row * 256 + SWZ(row, ks * 64 + lg * 16));
        }
        #pragma unroll
        for (int ct = 0; ct < 4; ++ct) {
            const int col = wc * 64 + ct * 16 + l15;
            bF[ct] = *(const bf8*)((const char*)B_lds + col * 256 + SWZ(col, ks * 64 + lg * 16));
        }
        #pragma unroll
        for (int rt = 0; rt < 2; ++rt)
            #pragma unroll
            for (int ct = 0; ct < 4; ++ct)
                acc[rt][ct] = __builtin_amdgcn_mfma_f32_16x16x32_bf16(aF[rt], bF[ct], acc[rt][ct], 0, 0, 0);
    }

    #pragma unroll
    for (int rt = 0; rt < 2; ++rt) {
        const int ltree = wr * 2 + rt;
        #pragma unroll
        for (int ct = 0; ct < 4; ++ct) {
            const int col = wc * 64 + ct * 16 + l15;
            const float bcv = bc[col];
            f32x4 v = acc[rt][ct];
            float m = -1e30f;
            #pragma unroll
            for (int r = 0; r < 4; ++r)
                m = fmaxf(m, v[r] + c_cnt[lg * 4 + r] * bcv);
            m = fmaxf(m, __shfl_xor(m, 16));
            m = fmaxf(m, __shfl_xor(m, 32));
            m = fmaxf(m, 0.f);
            if (lg == 0) {
                const int gtree = tree0 + ltree;
                const int row = (gtree & 127) * 64 + (gtree >> 7);   // t*64 + b
                enc_bf[((size_t)e * NTREE + row) * EE + col] = f2bf(m);
            }
        }
    }
}

// ---------------------------------------------------------------------------
// K3: fused GRU scan, LDS-resident. 64 blocks (e,dir,bgroup4) x 448 thr.
// The block's FULL enc slice (4 seqs x 128 t x 256B = 128KB) is staged into
// LDS once (XOR chunk^(c<<2) layout, <=2-way banks); the 128-step loop does
// ZERO global memory ops -> no vmcnt anywhere. Gate split: the 4 duplicated
// column groups each compute a different r (q=l15>>2): 1 gate-unit/lane,
// scalar gates, 2B h-write. Raw s_barrier + lgkmcnt(0), no clobber.
// ---------------------------------------------------------------------------
__global__ __launch_bounds__(448, 2) void k_gru(
    const unsigned short* __restrict__ enc_bf,
    const unsigned short* __restrict__ wih_pad,
    const unsigned short* __restrict__ whh_pad,
    const float* __restrict__ bih_f, const float* __restrict__ bih_b,
    const float* __restrict__ bhh_f, const float* __restrict__ bhh_b,
    float* __restrict__ hmax_out)
{
    __shared__ unsigned char enc_lds[4 * 128 * 256];  // 128KB [c][t][chunk^(c<<2)]
    __shared__ unsigned char h_lds[2][4 * 256];       // 2KB dbuf, rotated chunks
    const int tid  = threadIdx.x;
    const int blk  = blockIdx.x;        // 64
    const int e    = blk >> 5;
    const int dir  = (blk >> 4) & 1;
    const int b0   = (blk & 15) * 4;
    const int lane = tid & 63;
    const int l15  = lane & 15;
    const int lg   = lane >> 4;
    const int c    = l15 & 3;           // seq column
    const int q    = l15 >> 2;          // owned r-slot (gate split)
    const int jbase = (tid >> 6) * 16;
    const int j_own = jbase + lg * 4 + q;

    for (int u = tid; u < 512; u += 448)
        ((unsigned int*)h_lds)[u] = 0u;

    // stage enc slice into LDS: slot s -> (c = s>>11, t = (s>>4)&127, rc = s&15),
    // content = global chunk rc ^ (c<<2)  (so loop reads land conflict-light)
    #pragma unroll
    for (int i = 0; i < 19; ++i) {
        const int s = tid + i * 448;
        if (s < 8192) {
            const int sc = s >> 11, st = (s >> 4) & 127, rc = s & 15;
            const int gch = rc ^ (sc << 2);
            const u32x4 v = *(const u32x4*)(enc_bf
                + ((size_t)e * NTREE + st * 64 + b0 + sc) * EE + gch * 8);
            *(u32x4*)(enc_lds + s * 16) = v;
        }
    }

    // weight A-frags: row j = jbase + l15, k = ks*32 + lg*8
    bf8 aI[3][4], aH[3][4];
    {
        const unsigned short* wiP = wih_pad + (size_t)dir * 3 * 128 * 128;
        const unsigned short* whP = whh_pad + (size_t)dir * 3 * 128 * 128;
        #pragma unroll
        for (int g = 0; g < 3; ++g)
            #pragma unroll
            for (int ks = 0; ks < 4; ++ks) {
                const size_t ro = (size_t)(g * 128 + jbase + l15) * 128 + ks * 32 + lg * 8;
                aI[g][ks] = *(const bf8*)(wiP + ro);
                aH[g][ks] = *(const bf8*)(whP + ro);
            }
    }
    // biases folded into acc init: reg r <-> row j = jbase + lg*4 + r
    const float* __restrict__ bih = dir ? bih_b : bih_f;
    const float* __restrict__ bhh = dir ? bhh_b : bhh_f;
    f32x4 bR, bZ, bI_, bH_;
    #pragma unroll
    for (int r = 0; r < 4; ++r) {
        const int j = jbase + lg * 4 + r;
        bR[r]  = (j < 100) ? bih[j]       + bhh[j]       : 0.f;
        bZ[r]  = (j < 100) ? bih[100 + j] + bhh[100 + j] : 0.f;
        bI_[r] = (j < 100) ? bih[200 + j] : 0.f;
        bH_[r] = (j < 100) ? bhh[200 + j] : 0.f;
    }

    // constant per-lane LDS offsets
    unsigned int eoff[4], hoff[4];
    #pragma unroll
    for (int ks = 0; ks < 4; ++ks) {
        eoff[ks] = c * 32768 + ((((ks * 4 + lg) ^ (c << 2)) & 15) << 4);
        hoff[ks] = c * 256 + (((ks * 4 + lg + 4 * c) & 15) << 4);
    }
    const unsigned int hw_off = c * 256
        + ((((j_own >> 3) + 4 * c) & 15) << 4) + (j_own & 7) * 2;

    float h_cur = 0.f;
    float hmx   = -1e30f;
    __syncthreads();   // staging + h-zero complete (one-time drain, fine)

#define L2E  1.4426950408889634f
#define GRU_STEP(P, S)                                                         \
    {                                                                          \
        const int tm = dir ? (127 - (S)) : (S);                                \
        bf8 eF[4], hF[4];                                                      \
        _Pragma("unroll")                                                      \
        for (int ks = 0; ks < 4; ++ks)                                         \
            eF[ks] = *(const bf8*)(enc_lds + tm * 256 + eoff[ks]);             \
        _Pragma("unroll")                                                      \
        for (int ks = 0; ks < 4; ++ks)                                         \
            hF[ks] = *(const bf8*)(h_lds[P] + hoff[ks]);                       \
        f32x4 ar = bR, az = bZ, ai = bI_, ah = bH_;                            \
        _Pragma("unroll")                                                      \
        for (int ks = 0; ks < 4; ++ks) {                                       \
            ar = __builtin_amdgcn_mfma_f32_16x16x32_bf16(aI[0][ks], eF[ks], ar, 0, 0, 0); \
            az = __builtin_amdgcn_mfma_f32_16x16x32_bf16(aI[1][ks], eF[ks], az, 0, 0, 0); \
            ai = __builtin_amdgcn_mfma_f32_16x16x32_bf16(aI[2][ks], eF[ks], ai, 0, 0, 0); \
        }                                                                      \
        _Pragma("unroll")                                                      \
        for (int ks = 0; ks < 4; ++ks) {                                       \
            ar = __builtin_amdgcn_mfma_f32_16x16x32_bf16(aH[0][ks], hF[ks], ar, 0, 0, 0); \
            az = __builtin_amdgcn_mfma_f32_16x16x32_bf16(aH[1][ks], hF[ks], az, 0, 0, 0); \
            ah = __builtin_amdgcn_mfma_f32_16x16x32_bf16(aH[2][ks], hF[ks], ah, 0, 0, 0); \
        }                                                                      \
        const float gr  = selq(ar, q);                                         \
        const float gz  = selq(az, q);                                         \
        const float gi_ = selq(ai, q);                                         \
        const float gh_ = selq(ah, q);                                         \
        const float rg  = __builtin_amdgcn_rcpf(1.f + __builtin_amdgcn_exp2f(-L2E * gr)); \
        const float zg  = __builtin_amdgcn_rcpf(1.f + __builtin_amdgcn_exp2f(-L2E * gz)); \
        const float nx  = gi_ + rg * gh_;                                      \
        const float ng  = 1.f - 2.f * __builtin_amdgcn_rcpf(1.f + __builtin_amdgcn_exp2f((2.f * L2E) * nx)); \
        const float hnew = ng + zg * (h_cur - ng);                             \
        h_cur = hnew;                                                          \
        hmx = fmaxf(hmx, hnew);                                                \
        *(unsigned short*)(h_lds[(P) ^ 1] + hw_off) = f2bf(hnew);              \
        __builtin_amdgcn_sched_barrier(0);                                     \
        asm volatile("s_waitcnt lgkmcnt(0)");                                  \
        __builtin_amdgcn_s_barrier();                                          \
        __builtin_amdgcn_sched_barrier(0);                                     \
    }

    for (int t = 0; t < S_; t += 2) {
        GRU_STEP(0, t)
        GRU_STEP(1, t + 1)
    }
#undef GRU_STEP

    if (j_own < 100)
        hmax_out[((size_t)((e * 2 + dir) * 64 + b0 + c)) * HH + j_own] = hmx;
}

// ---------------------------------------------------------------------------
// K4: fc + softmax
// ---------------------------------------------------------------------------
__global__ void k_final(const float* __restrict__ hmax,
                        const float* __restrict__ fcw,
                        const float* __restrict__ fcb,
                        float* __restrict__ out)
{
    const int b = threadIdx.x;
    if (b >= B_) return;
    float y0 = fcb[0], y1 = fcb[1];
    for (int m = 0; m < 400; ++m) {
        const int e   = m / 200;
        const int dm  = m % 200;
        const int dir = dm / 100;
        const int j   = dm % 100;
        const float x = hmax[((size_t)((e * 2 + dir) * 64 + b)) * HH + j];
        y0 += fcw[m]       * x;
        y1 += fcw[400 + m] * x;
    }
    const float mx = fmaxf(y0, y1);
    const float e0 = __expf(y0 - mx), e1 = __expf(y1 - mx);
    const float s = e0 + e1;
    out[b * 2]     = e0 / s;
    out[b * 2 + 1] = e1 / s;
}

extern "C" void kernel_launch(void* const* d_in, const int* in_sizes, int n_in,
                              void* d_out, int out_size, void* d_ws, size_t ws_size,
                              hipStream_t stream)
{
    const int*   tok1  = (const int*)d_in[0];
    const int*   tok2  = (const int*)d_in[1];
    const float* emb   = (const float*)d_in[4];
    const float* Wc    = (const float*)d_in[5];
    const float* bc    = (const float*)d_in[6];
    const float* wih_f = (const float*)d_in[7];
    const float* whh_f = (const float*)d_in[8];
    const float* bih_f = (const float*)d_in[9];
    const float* bhh_f = (const float*)d_in[10];
    const float* wih_b = (const float*)d_in[11];
    const float* whh_b = (const float*)d_in[12];
    const float* bih_b = (const float*)d_in[13];
    const float* bhh_b = (const float*)d_in[14];
    const float* fcw   = (const float*)d_in[15];
    const float* fcb   = (const float*)d_in[16];

    char* ws = (char*)d_ws;
    unsigned short* emb_bf  = (unsigned short*)(ws + EMB_BF_OFF);
    unsigned short* wc_bf   = (unsigned short*)(ws + WC_BF_OFF);
    unsigned short* wih_pad = (unsigned short*)(ws + WIH_BF_OFF);
    unsigned short* whh_pad = (unsigned short*)(ws + WHH_BF_OFF);
    unsigned short* enc_bf  = (unsigned short*)(ws + ENC_BF_OFF);
    float*          hmax    = (float*)(ws + HMAX_OFF);

    k_prep<<<6458, 256, 0, stream>>>(emb, Wc, wih_f, wih_b, whh_f, whh_b,
                                     emb_bf, wc_bf, wih_pad, whh_pad);
    k_encode<<<2048, 512, 0, stream>>>(tok1, tok2, emb_bf, wc_bf, bc, enc_bf);
    k_gru<<<64, 448, 0, stream>>>(enc_bf, wih_pad, whh_pad,
                                  bih_f, bih_b, bhh_f, bhh_b, hmax);
    k_final<<<1, 64, 0, stream>>>(hmax, fcw, fcb, (float*)d_out);
}